// Round 18
// baseline (41.991 us; speedup 1.0000x reference)
//
#include <hip/hip_runtime.h>
#include <hip/hip_fp16.h>

#define CUT_SIZE 224
#define SIDE 1024
#define CUTN 128
#define NSLAB 8
#define SLAB_BLOCKS 192                 // 8*192 = 1536 blocks = 6/CU @ 24.8 KB LDS (co-resident)
#define SLAB_WSLOTS (SLAB_BLOCKS * 4)
#define LDSW2 1032                      // halves per channel row (max needed 1027) + slack

// d_ws (uint32 words): A[8][128] task-prefix | B[8][128] rlo | TOT[8]
#define WS_A     0
#define WS_B     (NSLAB * CUTN)
#define WS_TOT   (2 * NSLAB * CUTN)
#define WS_WORDS (2 * NSLAB * CUTN + NSLAB)

// ---------- plan: weighted equal-work slab quantiles (8-row granularity) ----------
__global__ __launch_bounds__(256) void plan_kernel(
    const int* __restrict__ sizes, const int* __restrict__ offy,
    unsigned int* __restrict__ ws)
{
    __shared__ float s_inv[CUTN], s_oy[CUTN];
    __shared__ int   s_wt[CUTN];
    __shared__ int   cdf[129];
    __shared__ int   qb[NSLAB + 1];
    __shared__ unsigned short slen[NSLAB][CUTN];
    const int t = threadIdx.x;

    if (t < CUTN) {
        const int sz = sizes[t];
        s_inv[t] = (float)CUT_SIZE / (float)sz;
        s_oy[t]  = (float)offy[t];
        s_wt[t]  = 100 + (sz >> 2);
    }
    __syncthreads();

    for (int k = t; k <= 128; k += 256) {
        const float Yf = (float)(k << 3);
        int c = 0;
        for (int n = 0; n < CUTN; ++n) {
            const float thr = (Yf + 0.5f - s_oy[n]) * s_inv[n] - 0.5f;
            c += min(CUT_SIZE, max(0, (int)ceilf(thr))) * s_wt[n];
        }
        cdf[k] = c;
    }
    __syncthreads();

    if (t >= 1 && t < NSLAB) {
        const long long target = (long long)t * (long long)cdf[128] / NSLAB;
        int lo = 0, hi = 128;
        while (hi - lo > 1) { const int m = (lo + hi) >> 1;
                              if ((long long)cdf[m] >= target) hi = m; else lo = m; }
        qb[t] = hi << 3;
    }
    if (t == 0) { qb[0] = 0; qb[NSLAB] = SIDE; }
    __syncthreads();

    for (int idx = t; idx < NSLAB * CUTN; idx += 256) {
        const int s = idx >> 7, n = idx & (CUTN - 1);
        int rlo, rhi;
        { const int Y = qb[s];
          rlo = (Y <= 0) ? 0
              : min(CUT_SIZE, max(0, (int)ceilf(((float)Y + 0.5f - s_oy[n]) * s_inv[n] - 0.5f))); }
        { const int Y = qb[s + 1];
          rhi = (Y >= SIDE) ? CUT_SIZE
              : min(CUT_SIZE, max(0, (int)ceilf(((float)Y + 0.5f - s_oy[n]) * s_inv[n] - 0.5f))); }
        slen[s][n] = (unsigned short)(rhi - rlo);
        ws[WS_B + idx] = (unsigned)rlo;
    }
    __syncthreads();

    if (t < NSLAB) {
        unsigned run = 0;
        for (int n = 0; n < CUTN; ++n) {
            ws[WS_A + t * CUTN + n] = run;
            run += slen[t][n];
        }
        ws[WS_TOT + t] = run;
    }
}

// ---------- main: r13 body + scheduler-freedom (unroll-2, no end clobber) ----------
// __launch_bounds__(256,6): 6 waves/SIMD minimum -> VGPR capped ~85 so the
// 24-wave/CU LDS-limited occupancy survives the unroll pressure.
__global__ __launch_bounds__(256, 6) void cutout_row_kernel(
    const float* __restrict__ img,     // [3, 1024, 1024]
    const int* __restrict__ sizes,
    const int* __restrict__ offy,
    const int* __restrict__ offx,
    const unsigned int* __restrict__ ws,
    float* __restrict__ out)           // [128, 3, 224, 224]
{
    __shared__ __half lds[4][3][LDSW2];             // 24.8 KB: wave-private 3-ch blended rows
    const int s    = blockIdx.x & 7;                // slab == XCD (co-resident grid)
    const int w    = threadIdx.x >> 6;
    const int lane = threadIdx.x & 63;
    const unsigned q = (unsigned)(blockIdx.x >> 3) * 4u + (unsigned)w;

    const unsigned* __restrict__ A = ws + WS_A + s * CUTN;
    const unsigned* __restrict__ B = ws + WS_B + s * CUTN;
    const unsigned T = ws[WS_TOT + s];
    __half* __restrict__ l0 = &lds[w][0][0];
    __half* __restrict__ l1 = &lds[w][1][0];
    __half* __restrict__ l2 = &lds[w][2][0];

    // Register-resident decode tables (two 64-entry halves per table, __shfl access).
    const unsigned aLo = A[lane],            aHi = A[64 + lane];
    const unsigned bLo = B[lane],            bHi = B[64 + lane];
    const float   szLo = (float)sizes[lane], szHi = (float)sizes[64 + lane];
    const float   oyLo = (float)offy[lane],  oyHi = (float)offy[64 + lane];
    const float   oxLo = (float)offx[lane],  oxHi = (float)offx[64 + lane];

    // Unroll 2: expose task i+1's staging loads to the scheduler during task i's
    // gather. Correctness of LDS reuse across tasks is carried by alias deps
    // (same lds array -> write-after-read preserved) + per-wave in-order DS.
#pragma unroll 2
    for (unsigned i = q; i < T; i += SLAB_WSLOTS) {
        // bit-descend bsearch over A via lane shuffles: max n with A[n] <= i.
        int n = 0;
        unsigned An = 0;                             // A[0] == 0
#pragma unroll
        for (int st = 64; st; st >>= 1) {
            const int m = n | st;                    // <= 127
            const unsigned Am = (m & 64) ? (unsigned)__shfl((int)aHi, m & 63)
                                         : (unsigned)__shfl((int)aLo, m & 63);
            if (Am <= i) { n = m; An = Am; }
        }
        const int hi6 = n & 64, lo6 = n & 63;
        const unsigned rlo = hi6 ? (unsigned)__shfl((int)bHi, lo6)
                                 : (unsigned)__shfl((int)bLo, lo6);
        const int   y  = (int)rlo + (int)(i - An);
        const float sz = hi6 ? __shfl(szHi, lo6) : __shfl(szLo, lo6);
        const float oy = hi6 ? __shfl(oyHi, lo6) : __shfl(oyLo, lo6);
        const float ox = hi6 ? __shfl(oxHi, lo6) : __shfl(oxLo, lo6);

        const float scale = sz * (1.0f / (float)CUT_SIZE);

        float fy = fmaf((float)y + 0.5f, scale, oy - 0.5f);
        fy = fminf(fmaxf(fy, 0.0f), (float)(SIDE - 1));
        const int   y0 = (int)fy;
        const int   y1 = min(y0 + 1, SIDE - 1);
        const float wy  = fy - (float)y0;
        const float wy0 = 1.0f - wy;

        // x span (wave-uniform per cutout)
        float fx0 = fmaf(0.5f, scale, ox - 0.5f);
        fx0 = fminf(fmaxf(fx0, 0.0f), (float)(SIDE - 1));
        float fxl = fmaf((float)CUT_SIZE - 0.5f, scale, ox - 0.5f);
        fxl = fminf(fmaxf(fxl, 0.0f), (float)(SIDE - 1));
        const int xb    = (int)fx0;
        const int xe    = min((int)fxl + 1, SIDE - 1);
        const int xb4   = xb & ~3;                  // 16B-aligned load base
        const int ilast = xe - xb4;
        const int nf4   = (ilast >> 2) + 1;         // wave-uniform float4 count (<=257)

        const size_t cstride = (size_t)SIDE * SIDE;
        const float* b0 = img + (size_t)y0 * SIDE + xb4;
        const float* b1 = img + (size_t)y1 * SIDE + xb4;
        const float4* __restrict__ rp0 = reinterpret_cast<const float4*>(b0);
        const float4* __restrict__ rq0 = reinterpret_cast<const float4*>(b1);
        const float4* __restrict__ rp1 = reinterpret_cast<const float4*>(b0 + cstride);
        const float4* __restrict__ rq1 = reinterpret_cast<const float4*>(b1 + cstride);
        const float4* __restrict__ rp2 = reinterpret_cast<const float4*>(b0 + 2 * cstride);
        const float4* __restrict__ rq2 = reinterpret_cast<const float4*>(b1 + 2 * cstride);

        // Stage all 3 channels: 6 independent L2-local float4 loads per iter.
        // Unroll 2: chunk k+1's loads issue before chunk k's blend (12 in flight).
#pragma unroll 2
        for (int k = lane; k < nf4; k += 64) {
            const float4 a0 = rp0[k], c0 = rq0[k];
            const float4 a1 = rp1[k], c1 = rq1[k];
            const float4 a2 = rp2[k], c2 = rq2[k];
            union { __half2 h[2]; uint2 u; } pk;
            pk.h[0] = __floats2half2_rn(a0.x * wy0 + c0.x * wy, a0.y * wy0 + c0.y * wy);
            pk.h[1] = __floats2half2_rn(a0.z * wy0 + c0.z * wy, a0.w * wy0 + c0.w * wy);
            *reinterpret_cast<uint2*>(l0 + 4 * k) = pk.u;
            pk.h[0] = __floats2half2_rn(a1.x * wy0 + c1.x * wy, a1.y * wy0 + c1.y * wy);
            pk.h[1] = __floats2half2_rn(a1.z * wy0 + c1.z * wy, a1.w * wy0 + c1.w * wy);
            *reinterpret_cast<uint2*>(l1 + 4 * k) = pk.u;
            pk.h[0] = __floats2half2_rn(a2.x * wy0 + c2.x * wy, a2.y * wy0 + c2.y * wy);
            pk.h[1] = __floats2half2_rn(a2.z * wy0 + c2.z * wy, a2.w * wy0 + c2.w * wy);
            *reinterpret_cast<uint2*>(l2 + 4 * k) = pk.u;
        }
        // Pad zero at ilast+1 (read only when wx==0; avoids stale-LDS NaN*0).
        if (lane < 3) (&lds[w][lane][0])[ilast + 1] = __float2half(0.0f);
        // Cross-lane LDS visibility: drain this wave's DS writes before reads.
        asm volatile("s_waitcnt lgkmcnt(0)" ::: "memory");

        // Gather: 4 consecutive px per lane (lanes 0..55), one float4 store/channel.
        const int p0 = lane << 2;
        if (p0 < CUT_SIZE) {
            const float xb4f = (float)xb4;
            float fx = fmaf((float)p0 + 0.5f, scale, ox - 0.5f);
            float4 o0, o1, o2;
            float* v0 = &o0.x; float* v1 = &o1.x; float* v2 = &o2.x;
#pragma unroll
            for (int j = 0; j < 4; ++j) {
                const float fxj = fminf(fmaxf(fx, 0.0f), (float)(SIDE - 1));
                fx += scale;                         // incremental column coordinate
                const float fl = fxj - xb4f;         // >= 0, <= ilast
                const int   i0 = (int)fl;
                const float wx  = fl - (float)i0;
                const float wx0 = 1.0f - wx;
                v0[j] = fminf(fmaxf(__half2float(l0[i0]) * wx0 + __half2float(l0[i0 + 1]) * wx, 0.0f), 1.0f);
                v1[j] = fminf(fmaxf(__half2float(l1[i0]) * wx0 + __half2float(l1[i0 + 1]) * wx, 0.0f), 1.0f);
                v2[j] = fminf(fmaxf(__half2float(l2[i0]) * wx0 + __half2float(l2[i0 + 1]) * wx, 0.0f), 1.0f);
            }
            const size_t obase = (((size_t)n * 3) * CUT_SIZE + y) * CUT_SIZE + p0;
            *reinterpret_cast<float4*>(out + obase) = o0;
            *reinterpret_cast<float4*>(out + obase + CUT_SIZE * CUT_SIZE) = o1;
            *reinterpret_cast<float4*>(out + obase + 2 * (CUT_SIZE * CUT_SIZE)) = o2;
        }
        // NOTE: no memory clobber here — next task's global loads are free to
        // hoist above this gather; LDS write-after-read order is kept by alias
        // dependencies on `lds` and per-wave in-order DS execution.
    }
}

// ---------- fallback (only if ws too small; known-correct round-3 structure) ----------
__global__ __launch_bounds__(128) void make_cutouts_fallback(
    const float* __restrict__ img, const int* __restrict__ sizes,
    const int* __restrict__ offy, const int* __restrict__ offx,
    float* __restrict__ out)
{
    __shared__ float lds[2][1032];
    const int n    = blockIdx.y;
    const int w    = threadIdx.x >> 6;
    const int lane = threadIdx.x & 63;
    const int y    = blockIdx.x * 2 + w;
    const float scale = (float)sizes[n] * (1.0f / (float)CUT_SIZE);
    const float oy = (float)offy[n];
    const float ox = (float)offx[n];
    float fy = fmaf((float)y + 0.5f, scale, oy - 0.5f);
    fy = fminf(fmaxf(fy, 0.0f), (float)(SIDE - 1));
    const int y0 = (int)fy, y1 = min(y0 + 1, SIDE - 1);
    const float wy = fy - (float)y0, wy0 = 1.0f - wy;
    float fx0 = fmaf(0.5f, scale, ox - 0.5f);
    fx0 = fminf(fmaxf(fx0, 0.0f), (float)(SIDE - 1));
    float fxl = fmaf((float)CUT_SIZE - 0.5f, scale, ox - 0.5f);
    fxl = fminf(fmaxf(fxl, 0.0f), (float)(SIDE - 1));
    const int xb = (int)fx0, xe = min((int)fxl + 1, SIDE - 1);
    const int xb4 = xb & ~3, ilast = xe - xb4, nf4 = (ilast >> 2) + 1;
    int i0r[4], i1r[4]; float wxr[4], wx0r[4];
#pragma unroll
    for (int it = 0; it < 4; ++it) {
        const int p = min(lane + it * 64, CUT_SIZE - 1);
        float fx = fmaf((float)p + 0.5f, scale, ox - 0.5f);
        fx = fminf(fmaxf(fx, 0.0f), (float)(SIDE - 1));
        const float fl = fx - (float)xb4;
        const int i0 = (int)fl;
        i0r[it] = i0; i1r[it] = min(i0 + 1, ilast);
        wxr[it] = fl - (float)i0; wx0r[it] = 1.0f - wxr[it];
    }
    const int r0off = y0 * SIDE + xb4, r1off = y1 * SIDE + xb4;
    float* __restrict__ l = lds[w];
    const size_t obase0 = (((size_t)n * 3) * CUT_SIZE + y) * CUT_SIZE;
    for (int c = 0; c < 3; ++c) {
        const float* __restrict__ ch = img + (size_t)c * (SIDE * SIDE);
        const float4* __restrict__ rp0 = reinterpret_cast<const float4*>(ch + r0off);
        const float4* __restrict__ rp1 = reinterpret_cast<const float4*>(ch + r1off);
        for (int k = lane; k < nf4; k += 64) {
            const float4 a = rp0[k]; const float4 b = rp1[k];
            float4 r;
            r.x = a.x * wy0 + b.x * wy; r.y = a.y * wy0 + b.y * wy;
            r.z = a.z * wy0 + b.z * wy; r.w = a.w * wy0 + b.w * wy;
            *reinterpret_cast<float4*>(l + 4 * k) = r;
        }
        asm volatile("s_waitcnt lgkmcnt(0)" ::: "memory");
        const size_t obase = obase0 + (size_t)c * (CUT_SIZE * CUT_SIZE);
#pragma unroll
        for (int it = 0; it < 4; ++it) {
            const int p = lane + it * 64;
            if (p < CUT_SIZE) {
                float v = l[i0r[it]] * wx0r[it] + l[i1r[it]] * wxr[it];
                v = fminf(fmaxf(v, 0.0f), 1.0f);
                out[obase + p] = v;
            }
        }
        asm volatile("" ::: "memory");
    }
}

extern "C" void kernel_launch(void* const* d_in, const int* in_sizes, int n_in,
                              void* d_out, int out_size, void* d_ws, size_t ws_size,
                              hipStream_t stream) {
    const float* img   = (const float*)d_in[0];
    const int*   sizes = (const int*)d_in[1];
    const int*   offy  = (const int*)d_in[2];
    const int*   offx  = (const int*)d_in[3];
    float*       out   = (float*)d_out;

    if (ws_size >= (size_t)WS_WORDS * 4) {
        unsigned int* ws = (unsigned int*)d_ws;
        plan_kernel<<<1, 256, 0, stream>>>(sizes, offy, ws);
        cutout_row_kernel<<<NSLAB * SLAB_BLOCKS, 256, 0, stream>>>(
            img, sizes, offy, offx, ws, out);
    } else {
        make_cutouts_fallback<<<dim3(CUT_SIZE / 2, CUTN), 128, 0, stream>>>(
            img, sizes, offy, offx, out);
    }
}

// Round 19
// 38.520 us; speedup vs baseline: 1.0901x; 1.0901x over previous
//
#include <hip/hip_runtime.h>
#include <hip/hip_fp16.h>

#define CUT_SIZE 224
#define SIDE 1024
#define CUTN 128
#define NSLAB 8
#define SLAB_BLOCKS 192                 // 8*192 = 1536 blocks = 6/CU @ 24.8 KB LDS (co-resident)
#define SLAB_WSLOTS (SLAB_BLOCKS * 4)
#define LDSW2 1032                      // halves per channel row (max needed 1027) + slack

// Single fused kernel: every block recomputes the (deterministic) slab plan in
// ~1-2K cycles using LDS scratch OVERLAID on the row buffer, then runs the r13
// champion row-task body unchanged. Removes the plan dispatch + grid-drain gap.
__global__ __launch_bounds__(256) void cutout_fused_kernel(
    const float* __restrict__ img,     // [3, 1024, 1024]
    const int* __restrict__ sizes,
    const int* __restrict__ offy,
    const int* __restrict__ offx,
    float* __restrict__ out)           // [128, 3, 224, 224]
{
    __shared__ __half lds[4][3][LDSW2];             // 24.8 KB: rows later, plan scratch now
    const int s    = blockIdx.x & 7;                // slab == XCD (co-resident grid)
    const int w    = threadIdx.x >> 6;
    const int lane = threadIdx.x & 63;
    const int t    = threadIdx.x;
    const unsigned q = (unsigned)(blockIdx.x >> 3) * 4u + (unsigned)w;

    // ---------- phase 0: fused plan (scratch overlaid on lds, ~3.6 KB) ----------
    float* pf  = reinterpret_cast<float*>(&lds[0][0][0]);
    int*   pi  = reinterpret_cast<int*>(&lds[0][0][0]);
    float* fInv = pf;                   // [0,128)   224/sz
    float* fOy  = pf + 128;             // [128,256)
    int*   iWt  = pi + 256;             // [256,384) row cost
    int*   cdf  = pi + 384;             // [384,513) weighted CDF @ Y=8k
    int*   qbv  = pi + 513;             // [513,522) slab boundaries
    int*   lenv = pi + 522;             // [522,650) rows of cutout n in slab s
    int*   rlov = pi + 650;             // [650,778) first such row
    int*   scv  = pi + 778;             // [778,906) inclusive scan of lenv

    if (t < CUTN) {
        const int sz = sizes[t];
        fInv[t] = (float)CUT_SIZE / (float)sz;
        fOy[t]  = (float)offy[t];
        iWt[t]  = 100 + (sz >> 2);      // cost model (same as r13 plan)
    }
    __syncthreads();

    if (t <= 128) {                     // weighted CDF, 129 sample points
        const float Yf = (float)(t << 3);
        int c = 0;
        for (int n = 0; n < CUTN; ++n) {
            const float thr = (Yf + 0.5f - fOy[n]) * fInv[n] - 0.5f;
            c += min(CUT_SIZE, max(0, (int)ceilf(thr))) * iWt[n];
        }
        cdf[t] = c;
    }
    __syncthreads();

    if (t >= 1 && t < NSLAB) {          // equal-work boundaries (8-row grid)
        const long long target = (long long)t * (long long)cdf[128] / NSLAB;
        int lo = 0, hi = 128;
        while (hi - lo > 1) { const int m = (lo + hi) >> 1;
                              if ((long long)cdf[m] >= target) hi = m; else lo = m; }
        qbv[t] = hi << 3;
    }
    if (t == 0) { qbv[0] = 0; qbv[NSLAB] = SIDE; }
    __syncthreads();

    if (t < CUTN) {                     // run of cutout t inside OUR slab s
        int rlo, rhi;
        { const int Y = qbv[s];
          rlo = (Y <= 0) ? 0
              : min(CUT_SIZE, max(0, (int)ceilf(((float)Y + 0.5f - fOy[t]) * fInv[t] - 0.5f))); }
        { const int Y = qbv[s + 1];
          rhi = (Y >= SIDE) ? CUT_SIZE
              : min(CUT_SIZE, max(0, (int)ceilf(((float)Y + 0.5f - fOy[t]) * fInv[t] - 0.5f))); }
        rlov[t] = rlo;
        lenv[t] = rhi - rlo;
        scv[t]  = rhi - rlo;
    }
    __syncthreads();
    // Hillis-Steele inclusive scan over scv[0..127] (7 steps)
    for (int off = 1; off < CUTN; off <<= 1) {
        int v = 0;
        if (t < CUTN && t >= off) v = scv[t - off];
        __syncthreads();
        if (t < CUTN) scv[t] += v;
        __syncthreads();
    }

    // ---------- load register decode tables, then release LDS for rows ----------
    const unsigned aLo = (unsigned)(scv[lane]      - lenv[lane]);        // exclusive prefix
    const unsigned aHi = (unsigned)(scv[64 + lane] - lenv[64 + lane]);
    const unsigned bLo = (unsigned)rlov[lane];
    const unsigned bHi = (unsigned)rlov[64 + lane];
    const unsigned T   = (unsigned)scv[CUTN - 1];
    const float   szLo = (float)sizes[lane], szHi = (float)sizes[64 + lane];
    const float   oyLo = (float)offy[lane],  oyHi = (float)offy[64 + lane];
    const float   oxLo = (float)offx[lane],  oxHi = (float)offx[64 + lane];
    __syncthreads();   // implicit lgkm drain: all scratch reads done before rows overwrite

    __half* __restrict__ l0 = &lds[w][0][0];
    __half* __restrict__ l1 = &lds[w][1][0];
    __half* __restrict__ l2 = &lds[w][2][0];

    // ---------- phase 1: r13 champion row-task body (byte-identical) ----------
    for (unsigned i = q; i < T; i += SLAB_WSLOTS) {
        // bit-descend bsearch over A via lane shuffles: max n with A[n] <= i.
        int n = 0;
        unsigned An = 0;                             // A[0] == 0
#pragma unroll
        for (int st = 64; st; st >>= 1) {
            const int m = n | st;                    // <= 127
            const unsigned Am = (m & 64) ? (unsigned)__shfl((int)aHi, m & 63)
                                         : (unsigned)__shfl((int)aLo, m & 63);
            if (Am <= i) { n = m; An = Am; }
        }
        const int hi6 = n & 64, lo6 = n & 63;
        const unsigned rlo = hi6 ? (unsigned)__shfl((int)bHi, lo6)
                                 : (unsigned)__shfl((int)bLo, lo6);
        const int   y  = (int)rlo + (int)(i - An);
        const float sz = hi6 ? __shfl(szHi, lo6) : __shfl(szLo, lo6);
        const float oy = hi6 ? __shfl(oyHi, lo6) : __shfl(oyLo, lo6);
        const float ox = hi6 ? __shfl(oxHi, lo6) : __shfl(oxLo, lo6);

        const float scale = sz * (1.0f / (float)CUT_SIZE);

        float fy = fmaf((float)y + 0.5f, scale, oy - 0.5f);
        fy = fminf(fmaxf(fy, 0.0f), (float)(SIDE - 1));
        const int   y0 = (int)fy;
        const int   y1 = min(y0 + 1, SIDE - 1);
        const float wy  = fy - (float)y0;
        const float wy0 = 1.0f - wy;

        // x span (wave-uniform per cutout)
        float fx0 = fmaf(0.5f, scale, ox - 0.5f);
        fx0 = fminf(fmaxf(fx0, 0.0f), (float)(SIDE - 1));
        float fxl = fmaf((float)CUT_SIZE - 0.5f, scale, ox - 0.5f);
        fxl = fminf(fmaxf(fxl, 0.0f), (float)(SIDE - 1));
        const int xb    = (int)fx0;
        const int xe    = min((int)fxl + 1, SIDE - 1);
        const int xb4   = xb & ~3;                  // 16B-aligned load base
        const int ilast = xe - xb4;
        const int nf4   = (ilast >> 2) + 1;         // wave-uniform float4 count (<=257)

        const size_t cstride = (size_t)SIDE * SIDE;
        const float* b0 = img + (size_t)y0 * SIDE + xb4;
        const float* b1 = img + (size_t)y1 * SIDE + xb4;
        const float4* __restrict__ rp0 = reinterpret_cast<const float4*>(b0);
        const float4* __restrict__ rq0 = reinterpret_cast<const float4*>(b1);
        const float4* __restrict__ rp1 = reinterpret_cast<const float4*>(b0 + cstride);
        const float4* __restrict__ rq1 = reinterpret_cast<const float4*>(b1 + cstride);
        const float4* __restrict__ rp2 = reinterpret_cast<const float4*>(b0 + 2 * cstride);
        const float4* __restrict__ rq2 = reinterpret_cast<const float4*>(b1 + 2 * cstride);

        // Stage all 3 channels: 6 independent L2-local float4 loads per iter.
        // Last load base col = xb4+4(nf4-1) <= xe <= 1023, 4-aligned: never OOB.
        for (int k = lane; k < nf4; k += 64) {
            const float4 a0 = rp0[k], c0 = rq0[k];
            const float4 a1 = rp1[k], c1 = rq1[k];
            const float4 a2 = rp2[k], c2 = rq2[k];
            union { __half2 h[2]; uint2 u; } pk;
            pk.h[0] = __floats2half2_rn(a0.x * wy0 + c0.x * wy, a0.y * wy0 + c0.y * wy);
            pk.h[1] = __floats2half2_rn(a0.z * wy0 + c0.z * wy, a0.w * wy0 + c0.w * wy);
            *reinterpret_cast<uint2*>(l0 + 4 * k) = pk.u;
            pk.h[0] = __floats2half2_rn(a1.x * wy0 + c1.x * wy, a1.y * wy0 + c1.y * wy);
            pk.h[1] = __floats2half2_rn(a1.z * wy0 + c1.z * wy, a1.w * wy0 + c1.w * wy);
            *reinterpret_cast<uint2*>(l1 + 4 * k) = pk.u;
            pk.h[0] = __floats2half2_rn(a2.x * wy0 + c2.x * wy, a2.y * wy0 + c2.y * wy);
            pk.h[1] = __floats2half2_rn(a2.z * wy0 + c2.z * wy, a2.w * wy0 + c2.w * wy);
            *reinterpret_cast<uint2*>(l2 + 4 * k) = pk.u;
        }
        // Pad zero at ilast+1 (read only when wx==0; avoids stale-LDS NaN*0).
        if (lane < 3) (&lds[w][lane][0])[ilast + 1] = __float2half(0.0f);
        // Wave-private LDS: one drain per task; "memory" stops reordering.
        asm volatile("s_waitcnt lgkmcnt(0)" ::: "memory");

        // Gather: 4 consecutive px per lane (lanes 0..55), one float4 store/channel.
        const int p0 = lane << 2;
        if (p0 < CUT_SIZE) {
            const float xb4f = (float)xb4;
            float fx = fmaf((float)p0 + 0.5f, scale, ox - 0.5f);
            float4 o0, o1, o2;
            float* v0 = &o0.x; float* v1 = &o1.x; float* v2 = &o2.x;
#pragma unroll
            for (int j = 0; j < 4; ++j) {
                const float fxj = fminf(fmaxf(fx, 0.0f), (float)(SIDE - 1));
                fx += scale;                         // incremental column coordinate
                const float fl = fxj - xb4f;         // >= 0, <= ilast
                const int   i0 = (int)fl;
                const float wx  = fl - (float)i0;
                const float wx0 = 1.0f - wx;
                v0[j] = fminf(fmaxf(__half2float(l0[i0]) * wx0 + __half2float(l0[i0 + 1]) * wx, 0.0f), 1.0f);
                v1[j] = fminf(fmaxf(__half2float(l1[i0]) * wx0 + __half2float(l1[i0 + 1]) * wx, 0.0f), 1.0f);
                v2[j] = fminf(fmaxf(__half2float(l2[i0]) * wx0 + __half2float(l2[i0 + 1]) * wx, 0.0f), 1.0f);
            }
            const size_t obase = (((size_t)n * 3) * CUT_SIZE + y) * CUT_SIZE + p0;
            *reinterpret_cast<float4*>(out + obase) = o0;
            *reinterpret_cast<float4*>(out + obase + CUT_SIZE * CUT_SIZE) = o1;
            *reinterpret_cast<float4*>(out + obase + 2 * (CUT_SIZE * CUT_SIZE)) = o2;
        }
        // Next task's ds_writes must not be hoisted past these ds_reads.
        asm volatile("" ::: "memory");
    }
}

extern "C" void kernel_launch(void* const* d_in, const int* in_sizes, int n_in,
                              void* d_out, int out_size, void* d_ws, size_t ws_size,
                              hipStream_t stream) {
    const float* img   = (const float*)d_in[0];
    const int*   sizes = (const int*)d_in[1];
    const int*   offy  = (const int*)d_in[2];
    const int*   offx  = (const int*)d_in[3];
    float*       out   = (float*)d_out;

    // Single fused dispatch: plan recomputed per block (deterministic), no d_ws.
    cutout_fused_kernel<<<NSLAB * SLAB_BLOCKS, 256, 0, stream>>>(
        img, sizes, offy, offx, out);
}